// Round 14
// baseline (413.307 us; speedup 1.0000x reference)
//
#include <hip/hip_runtime.h>
#include <math.h>

// R13: R12 (= R7 fused_all + amortized build_lut) + ONE isolated change:
//      the R10 zeroing diet (border-only zeroing; functionally verified in
//      R10, never costed alone). 19 -> ~5 f4 zero-stores/lane/pair.
// Ledger: R8(VGPR cap)=spill, R9(LDS diet)=occupancy pinned, R10(weave)=spill,
//         R11(de-pow2)=conflicts off critical path, R12(build_lut amortize)=-73us.

#define WR2_SZ 1664   // per-wave conv scratch float2s (4 waves * 1664 * 8B = 53248 B/block)
#define NL   16384    // LUT entries
#define ELUT 4        // entries per thread in build_lut

// Conjugated-rotation masks (verified absmax 0.0 in R2-R12).
constexpr int QM[7][8] = {
 {0x80,0x40,0x20,0x10,0x08,0x04,0x02,0x01},
 {0xC0,0x60,0x30,0x18,0x0C,0x06,0x03,0x01},
 {0xA0,0x50,0x28,0x14,0x0A,0x05,0x02,0x01},
 {0xF0,0x78,0x3C,0x1E,0x0F,0x07,0x03,0x01},
 {0x88,0x44,0x22,0x11,0x08,0x04,0x02,0x01},
 {0xCC,0x66,0x33,0x19,0x0C,0x06,0x03,0x01},
 {0xAA,0x55,0x2A,0x15,0x0A,0x05,0x02,0x01}};
constexpr int QR[7][8] = {
 {0x80,0x40,0x20,0x10,0x08,0x04,0x02,0x01},
 {0x80,0xC0,0xE0,0xF0,0xF8,0xFC,0xFE,0xFF},
 {0x80,0x40,0xA0,0x50,0xA8,0x54,0xAA,0x55},
 {0x80,0xC0,0x60,0x30,0x98,0xCC,0x66,0x33},
 {0x80,0x40,0x20,0x10,0x88,0x44,0x22,0x11},
 {0x80,0xC0,0xE0,0xF0,0x78,0x3C,0x1E,0x0F},
 {0x80,0x40,0xA0,0x50,0x28,0x14,0x0A,0x05}};

// One conjugated rotation on two float2-packed chain-pairs (4 samples).
#define ROTSTEP2(L, Q) { \
    constexpr int m_  = QM[L][Q]; \
    constexpr int r_  = QR[L][Q]; \
    constexpr int lm_ = m_ >> 2, rm_ = m_ & 3; \
    constexpr int rl_ = r_ >> 2, rr_ = r_ & 3; \
    constexpr float f1_ = (rr_ & 1) ? -1.f : 1.f; \
    constexpr float f2_ = (rr_ & 2) ? -1.f : 1.f; \
    constexpr float f3_ = f1_ * f2_; \
    const float c_ = qtc[(L) * 8 + (Q)]; \
    const float s_ = qts[(L) * 8 + (Q)]; \
    float sgn_; \
    if constexpr (rl_ != 0) sgn_ = (__popc(lane & rl_) & 1) ? s_ : -s_; \
    else                    sgn_ = -s_; \
    float2 pU0_ = sU[0 ^ rm_], pU1_ = sU[1 ^ rm_], pU2_ = sU[2 ^ rm_], pU3_ = sU[3 ^ rm_]; \
    float2 pV0_ = sV[0 ^ rm_], pV1_ = sV[1 ^ rm_], pV2_ = sV[2 ^ rm_], pV3_ = sV[3 ^ rm_]; \
    if constexpr (lm_ != 0) { \
        pU0_.x = __shfl_xor(pU0_.x, lm_); pU0_.y = __shfl_xor(pU0_.y, lm_); \
        pU1_.x = __shfl_xor(pU1_.x, lm_); pU1_.y = __shfl_xor(pU1_.y, lm_); \
        pU2_.x = __shfl_xor(pU2_.x, lm_); pU2_.y = __shfl_xor(pU2_.y, lm_); \
        pU3_.x = __shfl_xor(pU3_.x, lm_); pU3_.y = __shfl_xor(pU3_.y, lm_); \
        pV0_.x = __shfl_xor(pV0_.x, lm_); pV0_.y = __shfl_xor(pV0_.y, lm_); \
        pV1_.x = __shfl_xor(pV1_.x, lm_); pV1_.y = __shfl_xor(pV1_.y, lm_); \
        pV2_.x = __shfl_xor(pV2_.x, lm_); pV2_.y = __shfl_xor(pV2_.y, lm_); \
        pV3_.x = __shfl_xor(pV3_.x, lm_); pV3_.y = __shfl_xor(pV3_.y, lm_); \
    } \
    sU[0].x = fmaf(c_, sU[0].x, sgn_ * pU0_.x); \
    sU[0].y = fmaf(c_, sU[0].y, sgn_ * pU0_.y); \
    sU[1].x = fmaf(c_, sU[1].x, (f1_ * sgn_) * pU1_.x); \
    sU[1].y = fmaf(c_, sU[1].y, (f1_ * sgn_) * pU1_.y); \
    sU[2].x = fmaf(c_, sU[2].x, (f2_ * sgn_) * pU2_.x); \
    sU[2].y = fmaf(c_, sU[2].y, (f2_ * sgn_) * pU2_.y); \
    sU[3].x = fmaf(c_, sU[3].x, (f3_ * sgn_) * pU3_.x); \
    sU[3].y = fmaf(c_, sU[3].y, (f3_ * sgn_) * pU3_.y); \
    sV[0].x = fmaf(c_, sV[0].x, sgn_ * pV0_.x); \
    sV[0].y = fmaf(c_, sV[0].y, sgn_ * pV0_.y); \
    sV[1].x = fmaf(c_, sV[1].x, (f1_ * sgn_) * pV1_.x); \
    sV[1].y = fmaf(c_, sV[1].y, (f1_ * sgn_) * pV1_.y); \
    sV[2].x = fmaf(c_, sV[2].x, (f2_ * sgn_) * pV2_.x); \
    sV[2].y = fmaf(c_, sV[2].y, (f2_ * sgn_) * pV2_.y); \
    sV[3].x = fmaf(c_, sV[3].x, (f3_ * sgn_) * pV3_.x); \
    sV[3].y = fmaf(c_, sV[3].y, (f3_ * sgn_) * pV3_.y); \
}

#define ROTLAYER2(L) \
    ROTSTEP2(L,0) ROTSTEP2(L,1) ROTSTEP2(L,2) ROTSTEP2(L,3) \
    ROTSTEP2(L,4) ROTSTEP2(L,5) ROTSTEP2(L,6) ROTSTEP2(L,7)

// ---------------- LUT builder (R12: 4 entries/thread, weights amortized) ----------------
__global__ __launch_bounds__(128)
void build_lut(const float* __restrict__ w1, const float* __restrict__ b1,
               const float* __restrict__ w2, const float* __restrict__ b2,
               const float* __restrict__ w3, const float* __restrict__ b3,
               const float* __restrict__ w4, const float* __restrict__ b4,
               const float* __restrict__ w5, const float* __restrict__ b5,
               const float* __restrict__ qw,
               float* __restrict__ lut)
{
    __shared__ float hh[8][ELUT][344];
    const int tid = threadIdx.x;
    const int g = tid >> 4;
    const int w = tid & 15;
    const int idx0 = (blockIdx.x * 8 + g) * ELUT;

    if (blockIdx.x == 0 && tid < 56) {
        float th = 0.5f * qw[tid];
        lut[NL + tid]      = cosf(th);
        lut[NL + 56 + tid] = sinf(th);
    }

    float tv[ELUT];
    #pragma unroll
    for (int e = 0; e < ELUT; ++e)
        tv[e] = -1.f + 2.f * (float)(idx0 + e) / (float)(NL - 1);

    #pragma unroll
    for (int tt = 0; tt < 12; ++tt) {
        int j = tt * 16 + w;
        if (j < 180) {
            float wj = w1[j], bj = b1[j];
            #pragma unroll
            for (int e = 0; e < ELUT; ++e)
                hh[g][e][j] = fmaxf(fmaf(tv[e], wj, bj), 0.f);
        }
    }

    for (int tt = 0; tt < 9; ++tt) {
        int j = tt * 16 + w;
        int jj = (j < 140) ? j : 0;
        const float4* wrow = (const float4*)(w2 + jj * 180);
        float a0[ELUT] = {}, a1[ELUT] = {}, a2[ELUT] = {}, a3[ELUT] = {};
        for (int kc = 0; kc < 45; ++kc) {
            float4 ww = wrow[kc];
            #pragma unroll
            for (int e = 0; e < ELUT; ++e) {
                float4 h4 = *(const float4*)(&hh[g][e][kc * 4]);
                a0[e] = fmaf(h4.x, ww.x, a0[e]);
                a1[e] = fmaf(h4.y, ww.y, a1[e]);
                a2[e] = fmaf(h4.z, ww.z, a2[e]);
                a3[e] = fmaf(h4.w, ww.w, a3[e]);
            }
        }
        if (j < 140) {
            float bj = b2[j];
            #pragma unroll
            for (int e = 0; e < ELUT; ++e)
                hh[g][e][184 + j] = fmaxf((a0[e] + a1[e]) + (a2[e] + a3[e]) + bj, 0.f);
        }
    }

    for (int tt = 0; tt < 7; ++tt) {
        int j = tt * 16 + w;
        int jj = (j < 100) ? j : 0;
        const float4* wrow = (const float4*)(w3 + jj * 140);
        float a0[ELUT] = {}, a1[ELUT] = {}, a2[ELUT] = {}, a3[ELUT] = {};
        for (int kc = 0; kc < 35; ++kc) {
            float4 ww = wrow[kc];
            #pragma unroll
            for (int e = 0; e < ELUT; ++e) {
                float4 h4 = *(const float4*)(&hh[g][e][184 + kc * 4]);
                a0[e] = fmaf(h4.x, ww.x, a0[e]);
                a1[e] = fmaf(h4.y, ww.y, a1[e]);
                a2[e] = fmaf(h4.z, ww.z, a2[e]);
                a3[e] = fmaf(h4.w, ww.w, a3[e]);
            }
        }
        if (j < 100) {
            float bj = b3[j];
            #pragma unroll
            for (int e = 0; e < ELUT; ++e)
                hh[g][e][j] = fmaxf((a0[e] + a1[e]) + (a2[e] + a3[e]) + bj, 0.f);
        }
    }

    for (int tt = 0; tt < 4; ++tt) {
        int j = tt * 16 + w;
        int jj = (j < 50) ? j : 0;
        const float4* wrow = (const float4*)(w4 + jj * 100);
        float a0[ELUT] = {}, a1[ELUT] = {}, a2[ELUT] = {}, a3[ELUT] = {};
        for (int kc = 0; kc < 25; ++kc) {
            float4 ww = wrow[kc];
            #pragma unroll
            for (int e = 0; e < ELUT; ++e) {
                float4 h4 = *(const float4*)(&hh[g][e][kc * 4]);
                a0[e] = fmaf(h4.x, ww.x, a0[e]);
                a1[e] = fmaf(h4.y, ww.y, a1[e]);
                a2[e] = fmaf(h4.z, ww.z, a2[e]);
                a3[e] = fmaf(h4.w, ww.w, a3[e]);
            }
        }
        if (j < 50) {
            float bj = b4[j];
            #pragma unroll
            for (int e = 0; e < ELUT; ++e)
                hh[g][e][184 + j] = fmaxf((a0[e] + a1[e]) + (a2[e] + a3[e]) + bj, 0.f);
        }
    }

    float p5[ELUT] = {};
    for (int k = w; k < 50; k += 16) {
        float wk = w5[k];
        #pragma unroll
        for (int e = 0; e < ELUT; ++e)
            p5[e] = fmaf(hh[g][e][184 + k], wk, p5[e]);
    }
    #pragma unroll
    for (int m = 1; m < 16; m <<= 1) {
        #pragma unroll
        for (int e = 0; e < ELUT; ++e)
            p5[e] += __shfl_xor(p5[e], m);
    }
    if (w == 0) {
        float b5v = b5[0];
        #pragma unroll
        for (int e = 0; e < ELUT; ++e)
            lut[idx0 + e] = p5[e] + b5v;
    }
}

// ---------------- fused main kernel (R7 + border-only zeroing) ----------------
__global__ __launch_bounds__(256, 3)
void fused_all(const float* __restrict__ x,
               const float* __restrict__ c1w, const float* __restrict__ c1b,
               const float* __restrict__ c2w, const float* __restrict__ c2b,
               const float* __restrict__ c3w, const float* __restrict__ c3b,
               const float* __restrict__ fcw, const float* __restrict__ fcb,
               const float* __restrict__ lut,
               float* __restrict__ out, int B)
{
    __shared__ float2 wreg2[4][WR2_SZ];

    const int tid  = threadIdx.x;
    const int lane = tid & 63;
    const int wv   = tid >> 6;

    const float* qtc = lut + NL;
    const float* qts = lut + NL + 56;

    float2* wr2 = wreg2[wv];
    const int base = blockIdx.x * 16;

    float2* c1p2    = wr2;
    float2* pin2    = wr2 + 672;
    float2* c2pT2   = wr2 + 672;
    float2* c3_2    = wr2;
    float2* pooled2 = wr2 + 600;

    float2 sU[4], sV[4];

    const int o0 = lane * 4;
    const float4* fr0 = (const float4*)(fcw + (o0 + 0) * 48);
    const float4* fr1 = (const float4*)(fcw + (o0 + 1) * 48);
    const float4* fr2 = (const float4*)(fcw + (o0 + 2) * 48);
    const float4* fr3 = (const float4*)(fcw + (o0 + 3) * 48);
    const float4 fb = *(const float4*)(fcb + o0);

    #pragma unroll
    for (int pr = 0; pr < 2; ++pr) {
        int sa = base + wv * 4 + pr * 2;
        sa = (sa < B) ? sa : B - 1;
        const int sb = (sa + 1 < B) ? sa + 1 : sa;

        // ---- border-only zeroing (interior always fully overwritten) ----
        // pin2 [31][32] f2 = [31][16] f4: rows 0-1, row 30, side f4-cols 0/15
        {
            float4 z4 = {0.f, 0.f, 0.f, 0.f};
            float4* pf = (float4*)pin2;
            #pragma unroll
            for (int t = 0; t < 2; ++t) {
                int i = t * 64 + lane;
                if (i < 104) {
                    int idx_;
                    if (i < 32) idx_ = i;                                   // rows 0-1
                    else if (i < 48) idx_ = 480 + (i - 32);                 // row 30
                    else { int k = i - 48; idx_ = (2 + (k >> 1)) * 16 + (k & 1) * 15; } // sides
                    pf[idx_] = z4;
                }
            }
        }
        // c1p2 col-0 pads (read by conv2 at xx=0); prior pair's pooled2 is dead here
        if (lane < 42) {
            int c = lane / 14, y = lane % 14;
            c1p2[c * 224 + y * 16] = make_float2(0.f, 0.f);
        }

        // interleaved input load: pin2[i] = {xa[i], xb[i]}
        {
            const float4* xsA = (const float4*)(x + (size_t)sa * 784);
            const float4* xsB = (const float4*)(x + (size_t)sb * 784);
            #pragma unroll
            for (int t = 0; t < 4; ++t) {
                int i4 = t * 64 + lane;
                if (i4 < 196) {
                    float4 va = xsA[i4];
                    float4 vb = xsB[i4];
                    int r = i4 / 7;
                    int c = (i4 % 7) * 4;
                    float2* dst = pin2 + (r + 2) * 32 + (c + 2);
                    dst[0] = make_float2(va.x, vb.x);
                    dst[1] = make_float2(va.y, vb.y);
                    dst[2] = make_float2(va.z, vb.z);
                    dst[3] = make_float2(va.w, vb.w);
                }
            }
        }

        // ---- conv1: k5 s2 p2 -> c1p2 [3][14][16] (col+1) ----
        #pragma unroll
        for (int t = 0; t < 4; ++t) {
            int p = t * 64 + lane;
            bool valid = p < 196;
            int pp = valid ? p : 0;
            int y = pp / 14, xx = pp % 14;
            const float2* pr2 = pin2 + (2 * y) * 32 + 2 * xx;
            float2 win[25];
            #pragma unroll
            for (int ky = 0; ky < 5; ++ky) {
                const float2* rw = pr2 + ky * 32;
                #pragma unroll
                for (int j = 0; j < 5; ++j) win[ky * 5 + j] = rw[j];
            }
            #pragma unroll
            for (int c = 0; c < 3; ++c) {
                float ax = c1b[c], ay = c1b[c];
                #pragma unroll
                for (int k = 0; k < 25; ++k) {
                    float wk = c1w[c * 25 + k];
                    ax = fmaf(win[k].x, wk, ax);
                    ay = fmaf(win[k].y, wk, ay);
                }
                if (valid)
                    c1p2[c * 224 + y * 16 + (xx + 1)] =
                        make_float2(fmaxf(ax, 0.f), fmaxf(ay, 0.f));
            }
        }

        // ---- conv2: k3 s2 p1 -> c2pT2 [81][8]; zero only the 32 border positions ----
        {
            float4 z4 = {0.f, 0.f, 0.f, 0.f};
            float4* zz = (float4*)c2pT2;
            #pragma unroll
            for (int t = 0; t < 2; ++t) {
                int i = t * 64 + lane;
                int b = i >> 2;
                int p_;
                if (b < 9) p_ = b;                    // top row
                else if (b < 18) p_ = b + 63;         // bottom row (72..80)
                else if (b < 25) p_ = 9 * (b - 17);   // left col rows 1..7
                else p_ = 9 * (b - 24) + 8;           // right col rows 1..7
                zz[p_ * 4 + (i & 3)] = z4;
            }
        }
        {
            int p = lane;
            bool valid = p < 49;
            int pp = valid ? p : 0;
            int y = pp / 7, xx = pp % 7;
            float acx[6], acy[6];
            #pragma unroll
            for (int c = 0; c < 6; ++c) { acx[c] = c2b[c]; acy[c] = c2b[c]; }
            #pragma unroll
            for (int ic = 0; ic < 3; ++ic) {
                const float2* bic = c1p2 + ic * 224;
                float2 win[9];
                const float2 z2 = {0.f, 0.f};
                #pragma unroll
                for (int ky = 0; ky < 3; ++ky) {
                    int rr = 2 * y - 1 + ky;
                    bool okr = rr >= 0;
                    int rc = okr ? rr : 0;
                    const float2* rw = bic + rc * 16 + 2 * xx;
                    float2 a0 = rw[0], a1 = rw[1], a2 = rw[2];
                    win[ky * 3 + 0] = okr ? a0 : z2;
                    win[ky * 3 + 1] = okr ? a1 : z2;
                    win[ky * 3 + 2] = okr ? a2 : z2;
                }
                #pragma unroll
                for (int c = 0; c < 6; ++c)
                    #pragma unroll
                    for (int k = 0; k < 9; ++k) {
                        float wk = c2w[c * 27 + ic * 9 + k];
                        acx[c] = fmaf(win[k].x, wk, acx[c]);
                        acy[c] = fmaf(win[k].y, wk, acy[c]);
                    }
            }
            if (valid) {
                float2* op = c2pT2 + ((y + 1) * 9 + (xx + 1)) * 8;
                #pragma unroll
                for (int c = 0; c < 6; ++c)
                    op[c] = make_float2(fmaxf(acx[c], 0.f), fmaxf(acy[c], 0.f));
            }
        }

        // ---- conv3: k3 s1 p1 -> c3_2 (over dead c1p2) ----
        {
            int p = lane;
            bool valid = p < 49;
            int pp = valid ? p : 0;
            int y = pp / 7, xx = pp % 7;
            float acx[12], acy[12];
            #pragma unroll
            for (int c = 0; c < 12; ++c) { acx[c] = c3b[c]; acy[c] = c3b[c]; }
            #pragma unroll
            for (int dy = 0; dy < 3; ++dy)
                #pragma unroll
                for (int dx = 0; dx < 3; ++dx) {
                    const float2* cp = c2pT2 + ((y + dy) * 9 + (xx + dx)) * 8;
                    float2 ch[6];
                    #pragma unroll
                    for (int j = 0; j < 6; ++j) ch[j] = cp[j];
                    const int k = dy * 3 + dx;
                    #pragma unroll
                    for (int c = 0; c < 12; ++c) {
                        const float* wp = c3w + c * 54 + k;
                        #pragma unroll
                        for (int j = 0; j < 6; ++j) {
                            float wk = wp[j * 9];
                            acx[c] = fmaf(ch[j].x, wk, acx[c]);
                            acy[c] = fmaf(ch[j].y, wk, acy[c]);
                        }
                    }
                }
            if (valid) {
                #pragma unroll
                for (int c = 0; c < 12; ++c)
                    c3_2[c * 49 + p] = make_float2(fmaxf(acx[c], 0.f), fmaxf(acy[c], 0.f));
            }
        }

        // ---- adaptive pool -> pooled2 (LDS) ----
        {
            int o = lane;
            if (o < 48) {
                int c = o >> 2, i = (o >> 1) & 1, j = o & 1;
                int ri = i * 3, cj = j * 3;
                float sx = 0.f, sy = 0.f;
                #pragma unroll
                for (int dy = 0; dy < 4; ++dy)
                    #pragma unroll
                    for (int dx = 0; dx < 4; ++dx) {
                        float2 v = c3_2[c * 49 + (ri + dy) * 7 + (cj + dx)];
                        sx += v.x; sy += v.y;
                    }
                pooled2[o] = make_float2(sx * (1.f / 16.f), sy * (1.f / 16.f));
            }
        }

        // ---- fc 48->256 + relu + L2-normalize for the pair ----
        {
            float2 a0 = {0.f, 0.f}, a1 = {0.f, 0.f}, a2 = {0.f, 0.f}, a3 = {0.f, 0.f};
            #pragma unroll
            for (int kc = 0; kc < 12; ++kc) {
                float4 w0 = fr0[kc], w1 = fr1[kc], w2 = fr2[kc], w3 = fr3[kc];
                const float2* pv = pooled2 + kc * 4;
                float2 p0 = pv[0], p1 = pv[1], p2 = pv[2], p3 = pv[3];
                a0.x = fmaf(p0.x, w0.x, fmaf(p1.x, w0.y, fmaf(p2.x, w0.z, fmaf(p3.x, w0.w, a0.x))));
                a0.y = fmaf(p0.y, w0.x, fmaf(p1.y, w0.y, fmaf(p2.y, w0.z, fmaf(p3.y, w0.w, a0.y))));
                a1.x = fmaf(p0.x, w1.x, fmaf(p1.x, w1.y, fmaf(p2.x, w1.z, fmaf(p3.x, w1.w, a1.x))));
                a1.y = fmaf(p0.y, w1.x, fmaf(p1.y, w1.y, fmaf(p2.y, w1.z, fmaf(p3.y, w1.w, a1.y))));
                a2.x = fmaf(p0.x, w2.x, fmaf(p1.x, w2.y, fmaf(p2.x, w2.z, fmaf(p3.x, w2.w, a2.x))));
                a2.y = fmaf(p0.y, w2.x, fmaf(p1.y, w2.y, fmaf(p2.y, w2.z, fmaf(p3.y, w2.w, a2.y))));
                a3.x = fmaf(p0.x, w3.x, fmaf(p1.x, w3.y, fmaf(p2.x, w3.z, fmaf(p3.x, w3.w, a3.x))));
                a3.y = fmaf(p0.y, w3.x, fmaf(p1.y, w3.y, fmaf(p2.y, w3.z, fmaf(p3.y, w3.w, a3.y))));
            }
            float2 t0, t1, t2, t3;
            t0.x = fmaxf(a0.x + fb.x, 0.f); t0.y = fmaxf(a0.y + fb.x, 0.f);
            t1.x = fmaxf(a1.x + fb.y, 0.f); t1.y = fmaxf(a1.y + fb.y, 0.f);
            t2.x = fmaxf(a2.x + fb.z, 0.f); t2.y = fmaxf(a2.y + fb.z, 0.f);
            t3.x = fmaxf(a3.x + fb.w, 0.f); t3.y = fmaxf(a3.y + fb.w, 0.f);
            float ssx = fmaf(t0.x, t0.x, fmaf(t1.x, t1.x, fmaf(t2.x, t2.x, t3.x * t3.x)));
            float ssy = fmaf(t0.y, t0.y, fmaf(t1.y, t1.y, fmaf(t2.y, t2.y, t3.y * t3.y)));
            #pragma unroll
            for (int m = 1; m < 64; m <<= 1) {
                ssx += __shfl_xor(ssx, m);
                ssy += __shfl_xor(ssy, m);
            }
            float scx = 1.f / fmaxf(sqrtf(ssx), 1e-12f);
            float scy = 1.f / fmaxf(sqrtf(ssy), 1e-12f);
            t0.x *= scx; t1.x *= scx; t2.x *= scx; t3.x *= scx;
            t0.y *= scy; t1.y *= scy; t2.y *= scy; t3.y *= scy;
            if (pr == 0) { sU[0] = t0; sU[1] = t1; sU[2] = t2; sU[3] = t3; }
            else         { sV[0] = t0; sV[1] = t1; sV[2] = t2; sV[3] = t3; }
        }
    }

    // ---- qsim: 56 conjugated rotations on 2 packed chain-pairs (4 samples) ----
    ROTLAYER2(0) ROTLAYER2(1) ROTLAYER2(2) ROTLAYER2(3)
    ROTLAYER2(4) ROTLAYER2(5) ROTLAYER2(6)

    // ---- measurement: bit7 = lane bit5 ----
    float2 pU, pV;
    pU.x = sU[0].x*sU[0].x + sU[1].x*sU[1].x + sU[2].x*sU[2].x + sU[3].x*sU[3].x;
    pU.y = sU[0].y*sU[0].y + sU[1].y*sU[1].y + sU[2].y*sU[2].y + sU[3].y*sU[3].y;
    pV.x = sV[0].x*sV[0].x + sV[1].x*sV[1].x + sV[2].x*sV[2].x + sV[3].x*sV[3].x;
    pV.y = sV[0].y*sV[0].y + sV[1].y*sV[1].y + sV[2].y*sV[2].y + sV[3].y*sV[3].y;
    if (lane & 32) { pU.x = -pU.x; pU.y = -pU.y; pV.x = -pV.x; pV.y = -pV.y; }
    #pragma unroll
    for (int m = 1; m < 64; m <<= 1) {
        pU.x += __shfl_xor(pU.x, m); pU.y += __shfl_xor(pU.y, m);
        pV.x += __shfl_xor(pV.x, m); pV.y += __shfl_xor(pV.y, m);
    }

    if (lane < 4) {
        float qout = (lane == 0) ? pU.x : (lane == 1) ? pU.y : (lane == 2) ? pV.x : pV.y;
        int osample = base + wv * 4 + lane;
        float u = (qout + 1.f) * 0.5f * (float)(NL - 1);
        int i0 = (int)floorf(u);
        i0 = (i0 < 0) ? 0 : ((i0 > NL - 2) ? NL - 2 : i0);
        float fr = u - (float)i0;
        float z0 = lut[i0], z1 = lut[i0 + 1];
        float z = fmaf(z1 - z0, fr, z0);
        if (osample < B) out[osample] = 1.f / (1.f + expf(-z));
    }
}

extern "C" void kernel_launch(void* const* d_in, const int* in_sizes, int n_in,
                              void* d_out, int out_size, void* d_ws, size_t ws_size,
                              hipStream_t stream) {
    const float* x   = (const float*)d_in[0];
    const float* c1w = (const float*)d_in[1];
    const float* c1b = (const float*)d_in[2];
    const float* c2w = (const float*)d_in[3];
    const float* c2b = (const float*)d_in[4];
    const float* c3w = (const float*)d_in[5];
    const float* c3b = (const float*)d_in[6];
    const float* fcw = (const float*)d_in[7];
    const float* fcb = (const float*)d_in[8];
    const float* qw  = (const float*)d_in[9];
    const float* w1  = (const float*)d_in[10];
    const float* b1  = (const float*)d_in[11];
    const float* w2  = (const float*)d_in[12];
    const float* b2  = (const float*)d_in[13];
    const float* w3  = (const float*)d_in[14];
    const float* b3  = (const float*)d_in[15];
    const float* w4  = (const float*)d_in[16];
    const float* b4  = (const float*)d_in[17];
    const float* w5  = (const float*)d_in[18];
    const float* b5  = (const float*)d_in[19];

    float* lut = (float*)d_ws;   // [0,NL): z; [NL,NL+112): cos/sin

    int B = in_sizes[0] / 784;

    build_lut<<<dim3(NL / (8 * ELUT)), dim3(128), 0, stream>>>(
        w1, b1, w2, b2, w3, b3, w4, b4, w5, b5, qw, lut);

    int grid = (B + 15) / 16;
    fused_all<<<dim3(grid), dim3(256), 0, stream>>>(
        x, c1w, c1b, c2w, c2b, c3w, c3b, fcw, fcb, lut,
        (float*)d_out, B);
}

// Round 15
// 400.838 us; speedup vs baseline: 1.0311x; 1.0311x over previous
//
#include <hip/hip_runtime.h>
#include <math.h>

// R14: fused_all = EXACT R12/R7 (proven best, ~362us dispatch). build_lut
//      NL 16384 -> 8192 (halves its L2 weight-re-read traffic; lerp error
//      ~1.5e-3 vs 1.04e-2 threshold). No other changes.
// Ledger closed on fused_all: R8(VGPR cap)=spill, R9(LDS diet)=occupancy
// pinned ~12 waves/CU, R10(weave)=spill, R11(de-pow2)=conflicts off critical
// path, R13(zeroing diet)=neutral. Structure floor ~360us.

#define WR2_SZ 1664   // per-wave conv scratch float2s (4 waves * 1664 * 8B = 53248 B/block)
#define NL   8192     // LUT entries
#define ELUT 4        // entries per thread in build_lut

// Conjugated-rotation masks (verified absmax 0.0 in R2-R13).
constexpr int QM[7][8] = {
 {0x80,0x40,0x20,0x10,0x08,0x04,0x02,0x01},
 {0xC0,0x60,0x30,0x18,0x0C,0x06,0x03,0x01},
 {0xA0,0x50,0x28,0x14,0x0A,0x05,0x02,0x01},
 {0xF0,0x78,0x3C,0x1E,0x0F,0x07,0x03,0x01},
 {0x88,0x44,0x22,0x11,0x08,0x04,0x02,0x01},
 {0xCC,0x66,0x33,0x19,0x0C,0x06,0x03,0x01},
 {0xAA,0x55,0x2A,0x15,0x0A,0x05,0x02,0x01}};
constexpr int QR[7][8] = {
 {0x80,0x40,0x20,0x10,0x08,0x04,0x02,0x01},
 {0x80,0xC0,0xE0,0xF0,0xF8,0xFC,0xFE,0xFF},
 {0x80,0x40,0xA0,0x50,0xA8,0x54,0xAA,0x55},
 {0x80,0xC0,0x60,0x30,0x98,0xCC,0x66,0x33},
 {0x80,0x40,0x20,0x10,0x88,0x44,0x22,0x11},
 {0x80,0xC0,0xE0,0xF0,0x78,0x3C,0x1E,0x0F},
 {0x80,0x40,0xA0,0x50,0x28,0x14,0x0A,0x05}};

// One conjugated rotation on two float2-packed chain-pairs (4 samples).
#define ROTSTEP2(L, Q) { \
    constexpr int m_  = QM[L][Q]; \
    constexpr int r_  = QR[L][Q]; \
    constexpr int lm_ = m_ >> 2, rm_ = m_ & 3; \
    constexpr int rl_ = r_ >> 2, rr_ = r_ & 3; \
    constexpr float f1_ = (rr_ & 1) ? -1.f : 1.f; \
    constexpr float f2_ = (rr_ & 2) ? -1.f : 1.f; \
    constexpr float f3_ = f1_ * f2_; \
    const float c_ = qtc[(L) * 8 + (Q)]; \
    const float s_ = qts[(L) * 8 + (Q)]; \
    float sgn_; \
    if constexpr (rl_ != 0) sgn_ = (__popc(lane & rl_) & 1) ? s_ : -s_; \
    else                    sgn_ = -s_; \
    float2 pU0_ = sU[0 ^ rm_], pU1_ = sU[1 ^ rm_], pU2_ = sU[2 ^ rm_], pU3_ = sU[3 ^ rm_]; \
    float2 pV0_ = sV[0 ^ rm_], pV1_ = sV[1 ^ rm_], pV2_ = sV[2 ^ rm_], pV3_ = sV[3 ^ rm_]; \
    if constexpr (lm_ != 0) { \
        pU0_.x = __shfl_xor(pU0_.x, lm_); pU0_.y = __shfl_xor(pU0_.y, lm_); \
        pU1_.x = __shfl_xor(pU1_.x, lm_); pU1_.y = __shfl_xor(pU1_.y, lm_); \
        pU2_.x = __shfl_xor(pU2_.x, lm_); pU2_.y = __shfl_xor(pU2_.y, lm_); \
        pU3_.x = __shfl_xor(pU3_.x, lm_); pU3_.y = __shfl_xor(pU3_.y, lm_); \
        pV0_.x = __shfl_xor(pV0_.x, lm_); pV0_.y = __shfl_xor(pV0_.y, lm_); \
        pV1_.x = __shfl_xor(pV1_.x, lm_); pV1_.y = __shfl_xor(pV1_.y, lm_); \
        pV2_.x = __shfl_xor(pV2_.x, lm_); pV2_.y = __shfl_xor(pV2_.y, lm_); \
        pV3_.x = __shfl_xor(pV3_.x, lm_); pV3_.y = __shfl_xor(pV3_.y, lm_); \
    } \
    sU[0].x = fmaf(c_, sU[0].x, sgn_ * pU0_.x); \
    sU[0].y = fmaf(c_, sU[0].y, sgn_ * pU0_.y); \
    sU[1].x = fmaf(c_, sU[1].x, (f1_ * sgn_) * pU1_.x); \
    sU[1].y = fmaf(c_, sU[1].y, (f1_ * sgn_) * pU1_.y); \
    sU[2].x = fmaf(c_, sU[2].x, (f2_ * sgn_) * pU2_.x); \
    sU[2].y = fmaf(c_, sU[2].y, (f2_ * sgn_) * pU2_.y); \
    sU[3].x = fmaf(c_, sU[3].x, (f3_ * sgn_) * pU3_.x); \
    sU[3].y = fmaf(c_, sU[3].y, (f3_ * sgn_) * pU3_.y); \
    sV[0].x = fmaf(c_, sV[0].x, sgn_ * pV0_.x); \
    sV[0].y = fmaf(c_, sV[0].y, sgn_ * pV0_.y); \
    sV[1].x = fmaf(c_, sV[1].x, (f1_ * sgn_) * pV1_.x); \
    sV[1].y = fmaf(c_, sV[1].y, (f1_ * sgn_) * pV1_.y); \
    sV[2].x = fmaf(c_, sV[2].x, (f2_ * sgn_) * pV2_.x); \
    sV[2].y = fmaf(c_, sV[2].y, (f2_ * sgn_) * pV2_.y); \
    sV[3].x = fmaf(c_, sV[3].x, (f3_ * sgn_) * pV3_.x); \
    sV[3].y = fmaf(c_, sV[3].y, (f3_ * sgn_) * pV3_.y); \
}

#define ROTLAYER2(L) \
    ROTSTEP2(L,0) ROTSTEP2(L,1) ROTSTEP2(L,2) ROTSTEP2(L,3) \
    ROTSTEP2(L,4) ROTSTEP2(L,5) ROTSTEP2(L,6) ROTSTEP2(L,7)

// ---------------- LUT builder (R12 structure; NL=8192 -> 256 blocks) ----------------
__global__ __launch_bounds__(128)
void build_lut(const float* __restrict__ w1, const float* __restrict__ b1,
               const float* __restrict__ w2, const float* __restrict__ b2,
               const float* __restrict__ w3, const float* __restrict__ b3,
               const float* __restrict__ w4, const float* __restrict__ b4,
               const float* __restrict__ w5, const float* __restrict__ b5,
               const float* __restrict__ qw,
               float* __restrict__ lut)
{
    __shared__ float hh[8][ELUT][344];
    const int tid = threadIdx.x;
    const int g = tid >> 4;
    const int w = tid & 15;
    const int idx0 = (blockIdx.x * 8 + g) * ELUT;

    if (blockIdx.x == 0 && tid < 56) {
        float th = 0.5f * qw[tid];
        lut[NL + tid]      = cosf(th);
        lut[NL + 56 + tid] = sinf(th);
    }

    float tv[ELUT];
    #pragma unroll
    for (int e = 0; e < ELUT; ++e)
        tv[e] = -1.f + 2.f * (float)(idx0 + e) / (float)(NL - 1);

    #pragma unroll
    for (int tt = 0; tt < 12; ++tt) {
        int j = tt * 16 + w;
        if (j < 180) {
            float wj = w1[j], bj = b1[j];
            #pragma unroll
            for (int e = 0; e < ELUT; ++e)
                hh[g][e][j] = fmaxf(fmaf(tv[e], wj, bj), 0.f);
        }
    }

    for (int tt = 0; tt < 9; ++tt) {
        int j = tt * 16 + w;
        int jj = (j < 140) ? j : 0;
        const float4* wrow = (const float4*)(w2 + jj * 180);
        float a0[ELUT] = {}, a1[ELUT] = {}, a2[ELUT] = {}, a3[ELUT] = {};
        for (int kc = 0; kc < 45; ++kc) {
            float4 ww = wrow[kc];
            #pragma unroll
            for (int e = 0; e < ELUT; ++e) {
                float4 h4 = *(const float4*)(&hh[g][e][kc * 4]);
                a0[e] = fmaf(h4.x, ww.x, a0[e]);
                a1[e] = fmaf(h4.y, ww.y, a1[e]);
                a2[e] = fmaf(h4.z, ww.z, a2[e]);
                a3[e] = fmaf(h4.w, ww.w, a3[e]);
            }
        }
        if (j < 140) {
            float bj = b2[j];
            #pragma unroll
            for (int e = 0; e < ELUT; ++e)
                hh[g][e][184 + j] = fmaxf((a0[e] + a1[e]) + (a2[e] + a3[e]) + bj, 0.f);
        }
    }

    for (int tt = 0; tt < 7; ++tt) {
        int j = tt * 16 + w;
        int jj = (j < 100) ? j : 0;
        const float4* wrow = (const float4*)(w3 + jj * 140);
        float a0[ELUT] = {}, a1[ELUT] = {}, a2[ELUT] = {}, a3[ELUT] = {};
        for (int kc = 0; kc < 35; ++kc) {
            float4 ww = wrow[kc];
            #pragma unroll
            for (int e = 0; e < ELUT; ++e) {
                float4 h4 = *(const float4*)(&hh[g][e][184 + kc * 4]);
                a0[e] = fmaf(h4.x, ww.x, a0[e]);
                a1[e] = fmaf(h4.y, ww.y, a1[e]);
                a2[e] = fmaf(h4.z, ww.z, a2[e]);
                a3[e] = fmaf(h4.w, ww.w, a3[e]);
            }
        }
        if (j < 100) {
            float bj = b3[j];
            #pragma unroll
            for (int e = 0; e < ELUT; ++e)
                hh[g][e][j] = fmaxf((a0[e] + a1[e]) + (a2[e] + a3[e]) + bj, 0.f);
        }
    }

    for (int tt = 0; tt < 4; ++tt) {
        int j = tt * 16 + w;
        int jj = (j < 50) ? j : 0;
        const float4* wrow = (const float4*)(w4 + jj * 100);
        float a0[ELUT] = {}, a1[ELUT] = {}, a2[ELUT] = {}, a3[ELUT] = {};
        for (int kc = 0; kc < 25; ++kc) {
            float4 ww = wrow[kc];
            #pragma unroll
            for (int e = 0; e < ELUT; ++e) {
                float4 h4 = *(const float4*)(&hh[g][e][kc * 4]);
                a0[e] = fmaf(h4.x, ww.x, a0[e]);
                a1[e] = fmaf(h4.y, ww.y, a1[e]);
                a2[e] = fmaf(h4.z, ww.z, a2[e]);
                a3[e] = fmaf(h4.w, ww.w, a3[e]);
            }
        }
        if (j < 50) {
            float bj = b4[j];
            #pragma unroll
            for (int e = 0; e < ELUT; ++e)
                hh[g][e][184 + j] = fmaxf((a0[e] + a1[e]) + (a2[e] + a3[e]) + bj, 0.f);
        }
    }

    float p5[ELUT] = {};
    for (int k = w; k < 50; k += 16) {
        float wk = w5[k];
        #pragma unroll
        for (int e = 0; e < ELUT; ++e)
            p5[e] = fmaf(hh[g][e][184 + k], wk, p5[e]);
    }
    #pragma unroll
    for (int m = 1; m < 16; m <<= 1) {
        #pragma unroll
        for (int e = 0; e < ELUT; ++e)
            p5[e] += __shfl_xor(p5[e], m);
    }
    if (w == 0) {
        float b5v = b5[0];
        #pragma unroll
        for (int e = 0; e < ELUT; ++e)
            lut[idx0 + e] = p5[e] + b5v;
    }
}

// ---------------- fused main kernel (EXACT R12/R7) ----------------
__global__ __launch_bounds__(256, 3)
void fused_all(const float* __restrict__ x,
               const float* __restrict__ c1w, const float* __restrict__ c1b,
               const float* __restrict__ c2w, const float* __restrict__ c2b,
               const float* __restrict__ c3w, const float* __restrict__ c3b,
               const float* __restrict__ fcw, const float* __restrict__ fcb,
               const float* __restrict__ lut,
               float* __restrict__ out, int B)
{
    __shared__ float2 wreg2[4][WR2_SZ];

    const int tid  = threadIdx.x;
    const int lane = tid & 63;
    const int wv   = tid >> 6;

    const float* qtc = lut + NL;
    const float* qts = lut + NL + 56;

    float2* wr2 = wreg2[wv];
    const int base = blockIdx.x * 16;

    float2* c1p2    = wr2;
    float2* pin2    = wr2 + 672;
    float2* c2pT2   = wr2 + 672;
    float2* c3_2    = wr2;
    float2* pooled2 = wr2 + 600;

    float2 sU[4], sV[4];

    const int o0 = lane * 4;
    const float4* fr0 = (const float4*)(fcw + (o0 + 0) * 48);
    const float4* fr1 = (const float4*)(fcw + (o0 + 1) * 48);
    const float4* fr2 = (const float4*)(fcw + (o0 + 2) * 48);
    const float4* fr3 = (const float4*)(fcw + (o0 + 3) * 48);
    const float4 fb = *(const float4*)(fcb + o0);

    #pragma unroll
    for (int pr = 0; pr < 2; ++pr) {
        int sa = base + wv * 4 + pr * 2;
        sa = (sa < B) ? sa : B - 1;
        const int sb = (sa + 1 < B) ? sa + 1 : sa;

        {
            float4 z4 = {0.f, 0.f, 0.f, 0.f};
            float* w0 = (float*)wr2;
            #pragma unroll
            for (int t = 0; t < 13; ++t)
                *(float4*)(w0 + t * 256 + lane * 4) = z4;
        }
        {
            const float4* xsA = (const float4*)(x + (size_t)sa * 784);
            const float4* xsB = (const float4*)(x + (size_t)sb * 784);
            #pragma unroll
            for (int t = 0; t < 4; ++t) {
                int i4 = t * 64 + lane;
                if (i4 < 196) {
                    float4 va = xsA[i4];
                    float4 vb = xsB[i4];
                    int r = i4 / 7;
                    int c = (i4 % 7) * 4;
                    float2* dst = pin2 + (r + 2) * 32 + (c + 2);
                    dst[0] = make_float2(va.x, vb.x);
                    dst[1] = make_float2(va.y, vb.y);
                    dst[2] = make_float2(va.z, vb.z);
                    dst[3] = make_float2(va.w, vb.w);
                }
            }
        }

        // ---- conv1: k5 s2 p2 -> c1p2 [3][14][16] (col+1) ----
        #pragma unroll
        for (int t = 0; t < 4; ++t) {
            int p = t * 64 + lane;
            bool valid = p < 196;
            int pp = valid ? p : 0;
            int y = pp / 14, xx = pp % 14;
            const float2* pr2 = pin2 + (2 * y) * 32 + 2 * xx;
            float2 win[25];
            #pragma unroll
            for (int ky = 0; ky < 5; ++ky) {
                const float2* rw = pr2 + ky * 32;
                #pragma unroll
                for (int j = 0; j < 5; ++j) win[ky * 5 + j] = rw[j];
            }
            #pragma unroll
            for (int c = 0; c < 3; ++c) {
                float ax = c1b[c], ay = c1b[c];
                #pragma unroll
                for (int k = 0; k < 25; ++k) {
                    float wk = c1w[c * 25 + k];
                    ax = fmaf(win[k].x, wk, ax);
                    ay = fmaf(win[k].y, wk, ay);
                }
                if (valid)
                    c1p2[c * 224 + y * 16 + (xx + 1)] =
                        make_float2(fmaxf(ax, 0.f), fmaxf(ay, 0.f));
            }
        }

        // ---- conv2: k3 s2 p1 -> c2pT2 [81][8] (row-masked top row) ----
        {
            float4 z4 = {0.f, 0.f, 0.f, 0.f};
            float4* zz = (float4*)c2pT2;
            #pragma unroll
            for (int t = 0; t < 6; ++t) {
                int i = t * 64 + lane;
                if (i < 324) zz[i] = z4;
            }
        }
        {
            int p = lane;
            bool valid = p < 49;
            int pp = valid ? p : 0;
            int y = pp / 7, xx = pp % 7;
            float acx[6], acy[6];
            #pragma unroll
            for (int c = 0; c < 6; ++c) { acx[c] = c2b[c]; acy[c] = c2b[c]; }
            #pragma unroll
            for (int ic = 0; ic < 3; ++ic) {
                const float2* bic = c1p2 + ic * 224;
                float2 win[9];
                const float2 z2 = {0.f, 0.f};
                #pragma unroll
                for (int ky = 0; ky < 3; ++ky) {
                    int rr = 2 * y - 1 + ky;
                    bool okr = rr >= 0;
                    int rc = okr ? rr : 0;
                    const float2* rw = bic + rc * 16 + 2 * xx;
                    float2 a0 = rw[0], a1 = rw[1], a2 = rw[2];
                    win[ky * 3 + 0] = okr ? a0 : z2;
                    win[ky * 3 + 1] = okr ? a1 : z2;
                    win[ky * 3 + 2] = okr ? a2 : z2;
                }
                #pragma unroll
                for (int c = 0; c < 6; ++c)
                    #pragma unroll
                    for (int k = 0; k < 9; ++k) {
                        float wk = c2w[c * 27 + ic * 9 + k];
                        acx[c] = fmaf(win[k].x, wk, acx[c]);
                        acy[c] = fmaf(win[k].y, wk, acy[c]);
                    }
            }
            if (valid) {
                float2* op = c2pT2 + ((y + 1) * 9 + (xx + 1)) * 8;
                #pragma unroll
                for (int c = 0; c < 6; ++c)
                    op[c] = make_float2(fmaxf(acx[c], 0.f), fmaxf(acy[c], 0.f));
            }
        }

        // ---- conv3: k3 s1 p1 -> c3_2 (over dead c1p2) ----
        {
            int p = lane;
            bool valid = p < 49;
            int pp = valid ? p : 0;
            int y = pp / 7, xx = pp % 7;
            float acx[12], acy[12];
            #pragma unroll
            for (int c = 0; c < 12; ++c) { acx[c] = c3b[c]; acy[c] = c3b[c]; }
            #pragma unroll
            for (int dy = 0; dy < 3; ++dy)
                #pragma unroll
                for (int dx = 0; dx < 3; ++dx) {
                    const float2* cp = c2pT2 + ((y + dy) * 9 + (xx + dx)) * 8;
                    float2 ch[6];
                    #pragma unroll
                    for (int j = 0; j < 6; ++j) ch[j] = cp[j];
                    const int k = dy * 3 + dx;
                    #pragma unroll
                    for (int c = 0; c < 12; ++c) {
                        const float* wp = c3w + c * 54 + k;
                        #pragma unroll
                        for (int j = 0; j < 6; ++j) {
                            float wk = wp[j * 9];
                            acx[c] = fmaf(ch[j].x, wk, acx[c]);
                            acy[c] = fmaf(ch[j].y, wk, acy[c]);
                        }
                    }
                }
            if (valid) {
                #pragma unroll
                for (int c = 0; c < 12; ++c)
                    c3_2[c * 49 + p] = make_float2(fmaxf(acx[c], 0.f), fmaxf(acy[c], 0.f));
            }
        }

        // ---- adaptive pool -> pooled2 (LDS) ----
        {
            int o = lane;
            if (o < 48) {
                int c = o >> 2, i = (o >> 1) & 1, j = o & 1;
                int ri = i * 3, cj = j * 3;
                float sx = 0.f, sy = 0.f;
                #pragma unroll
                for (int dy = 0; dy < 4; ++dy)
                    #pragma unroll
                    for (int dx = 0; dx < 4; ++dx) {
                        float2 v = c3_2[c * 49 + (ri + dy) * 7 + (cj + dx)];
                        sx += v.x; sy += v.y;
                    }
                pooled2[o] = make_float2(sx * (1.f / 16.f), sy * (1.f / 16.f));
            }
        }

        // ---- fc 48->256 + relu + L2-normalize for the pair ----
        {
            float2 a0 = {0.f, 0.f}, a1 = {0.f, 0.f}, a2 = {0.f, 0.f}, a3 = {0.f, 0.f};
            #pragma unroll
            for (int kc = 0; kc < 12; ++kc) {
                float4 w0 = fr0[kc], w1 = fr1[kc], w2 = fr2[kc], w3 = fr3[kc];
                const float2* pv = pooled2 + kc * 4;
                float2 p0 = pv[0], p1 = pv[1], p2 = pv[2], p3 = pv[3];
                a0.x = fmaf(p0.x, w0.x, fmaf(p1.x, w0.y, fmaf(p2.x, w0.z, fmaf(p3.x, w0.w, a0.x))));
                a0.y = fmaf(p0.y, w0.x, fmaf(p1.y, w0.y, fmaf(p2.y, w0.z, fmaf(p3.y, w0.w, a0.y))));
                a1.x = fmaf(p0.x, w1.x, fmaf(p1.x, w1.y, fmaf(p2.x, w1.z, fmaf(p3.x, w1.w, a1.x))));
                a1.y = fmaf(p0.y, w1.x, fmaf(p1.y, w1.y, fmaf(p2.y, w1.z, fmaf(p3.y, w1.w, a1.y))));
                a2.x = fmaf(p0.x, w2.x, fmaf(p1.x, w2.y, fmaf(p2.x, w2.z, fmaf(p3.x, w2.w, a2.x))));
                a2.y = fmaf(p0.y, w2.x, fmaf(p1.y, w2.y, fmaf(p2.y, w2.z, fmaf(p3.y, w2.w, a2.y))));
                a3.x = fmaf(p0.x, w3.x, fmaf(p1.x, w3.y, fmaf(p2.x, w3.z, fmaf(p3.x, w3.w, a3.x))));
                a3.y = fmaf(p0.y, w3.x, fmaf(p1.y, w3.y, fmaf(p2.y, w3.z, fmaf(p3.y, w3.w, a3.y))));
            }
            float2 t0, t1, t2, t3;
            t0.x = fmaxf(a0.x + fb.x, 0.f); t0.y = fmaxf(a0.y + fb.x, 0.f);
            t1.x = fmaxf(a1.x + fb.y, 0.f); t1.y = fmaxf(a1.y + fb.y, 0.f);
            t2.x = fmaxf(a2.x + fb.z, 0.f); t2.y = fmaxf(a2.y + fb.z, 0.f);
            t3.x = fmaxf(a3.x + fb.w, 0.f); t3.y = fmaxf(a3.y + fb.w, 0.f);
            float ssx = fmaf(t0.x, t0.x, fmaf(t1.x, t1.x, fmaf(t2.x, t2.x, t3.x * t3.x)));
            float ssy = fmaf(t0.y, t0.y, fmaf(t1.y, t1.y, fmaf(t2.y, t2.y, t3.y * t3.y)));
            #pragma unroll
            for (int m = 1; m < 64; m <<= 1) {
                ssx += __shfl_xor(ssx, m);
                ssy += __shfl_xor(ssy, m);
            }
            float scx = 1.f / fmaxf(sqrtf(ssx), 1e-12f);
            float scy = 1.f / fmaxf(sqrtf(ssy), 1e-12f);
            t0.x *= scx; t1.x *= scx; t2.x *= scx; t3.x *= scx;
            t0.y *= scy; t1.y *= scy; t2.y *= scy; t3.y *= scy;
            if (pr == 0) { sU[0] = t0; sU[1] = t1; sU[2] = t2; sU[3] = t3; }
            else         { sV[0] = t0; sV[1] = t1; sV[2] = t2; sV[3] = t3; }
        }
    }

    // ---- qsim: 56 conjugated rotations on 2 packed chain-pairs (4 samples) ----
    ROTLAYER2(0) ROTLAYER2(1) ROTLAYER2(2) ROTLAYER2(3)
    ROTLAYER2(4) ROTLAYER2(5) ROTLAYER2(6)

    // ---- measurement: bit7 = lane bit5 ----
    float2 pU, pV;
    pU.x = sU[0].x*sU[0].x + sU[1].x*sU[1].x + sU[2].x*sU[2].x + sU[3].x*sU[3].x;
    pU.y = sU[0].y*sU[0].y + sU[1].y*sU[1].y + sU[2].y*sU[2].y + sU[3].y*sU[3].y;
    pV.x = sV[0].x*sV[0].x + sV[1].x*sV[1].x + sV[2].x*sV[2].x + sV[3].x*sV[3].x;
    pV.y = sV[0].y*sV[0].y + sV[1].y*sV[1].y + sV[2].y*sV[2].y + sV[3].y*sV[3].y;
    if (lane & 32) { pU.x = -pU.x; pU.y = -pU.y; pV.x = -pV.x; pV.y = -pV.y; }
    #pragma unroll
    for (int m = 1; m < 64; m <<= 1) {
        pU.x += __shfl_xor(pU.x, m); pU.y += __shfl_xor(pU.y, m);
        pV.x += __shfl_xor(pV.x, m); pV.y += __shfl_xor(pV.y, m);
    }

    if (lane < 4) {
        float qout = (lane == 0) ? pU.x : (lane == 1) ? pU.y : (lane == 2) ? pV.x : pV.y;
        int osample = base + wv * 4 + lane;
        float u = (qout + 1.f) * 0.5f * (float)(NL - 1);
        int i0 = (int)floorf(u);
        i0 = (i0 < 0) ? 0 : ((i0 > NL - 2) ? NL - 2 : i0);
        float fr = u - (float)i0;
        float z0 = lut[i0], z1 = lut[i0 + 1];
        float z = fmaf(z1 - z0, fr, z0);
        if (osample < B) out[osample] = 1.f / (1.f + expf(-z));
    }
}

extern "C" void kernel_launch(void* const* d_in, const int* in_sizes, int n_in,
                              void* d_out, int out_size, void* d_ws, size_t ws_size,
                              hipStream_t stream) {
    const float* x   = (const float*)d_in[0];
    const float* c1w = (const float*)d_in[1];
    const float* c1b = (const float*)d_in[2];
    const float* c2w = (const float*)d_in[3];
    const float* c2b = (const float*)d_in[4];
    const float* c3w = (const float*)d_in[5];
    const float* c3b = (const float*)d_in[6];
    const float* fcw = (const float*)d_in[7];
    const float* fcb = (const float*)d_in[8];
    const float* qw  = (const float*)d_in[9];
    const float* w1  = (const float*)d_in[10];
    const float* b1  = (const float*)d_in[11];
    const float* w2  = (const float*)d_in[12];
    const float* b2  = (const float*)d_in[13];
    const float* w3  = (const float*)d_in[14];
    const float* b3  = (const float*)d_in[15];
    const float* w4  = (const float*)d_in[16];
    const float* b4  = (const float*)d_in[17];
    const float* w5  = (const float*)d_in[18];
    const float* b5  = (const float*)d_in[19];

    float* lut = (float*)d_ws;   // [0,NL): z; [NL,NL+112): cos/sin

    int B = in_sizes[0] / 784;

    build_lut<<<dim3(NL / (8 * ELUT)), dim3(128), 0, stream>>>(
        w1, b1, w2, b2, w3, b3, w4, b4, w5, b5, qw, lut);

    int grid = (B + 15) / 16;
    fused_all<<<dim3(grid), dim3(256), 0, stream>>>(
        x, c1w, c1b, c2w, c2b, c3w, c3b, fcw, fcb, lut,
        (float*)d_out, B);
}